// Round 3
// baseline (229.898 us; speedup 1.0000x reference)
//
#include <hip/hip_runtime.h>
#include <hip/hip_bf16.h>
#include <stdint.h>

// Problem: B=2, T=2048, D=1024, H=16, hd=64.  M = B*T = 4096.
// Pipeline: x->bf16 ; w^T->bf16 ; QKV gemm w/ fused bias+RoPE+head-split ; flash attn ; out gemm.
// Workspace layout (bytes), total 50,331,648 (48 MiB -- must stay < 64 MiB, see R2 post-mortem):
//   0        x_bf16   [4096][1024]
//   8388608  wqkvT    [3072][1024]
//   14680064 woutT    [1024][1024]
//   16777216 Q        [32][2048][64]   (pre-scaled by log2e/8, RoPE'd)
//   25165824 K        [32][2048][64]   (RoPE'd)
//   33554432 V        [32][2048][64]
//   41943040 attn     [4096][1024]

typedef __bf16 bf16;
typedef __bf16 bf16x8 __attribute__((ext_vector_type(8)));
typedef __bf16 bf16x4 __attribute__((ext_vector_type(4)));
typedef float  f32x4  __attribute__((ext_vector_type(4)));

__device__ __forceinline__ void gload16(void* lds, const void* g) {
  // async global->LDS, 16B per lane, dest = wave-uniform base + lane*16
  __builtin_amdgcn_global_load_lds((__attribute__((address_space(1))) void*)(void*)g,
                                   (__attribute__((address_space(3))) void*)lds, 16, 0, 0);
}

// ---------------- conversion kernels ----------------

__global__ void k_convert_x(const float* __restrict__ x, bf16* __restrict__ xb, int n) {
  int i = (blockIdx.x * blockDim.x + threadIdx.x) * 4;
  if (i >= n) return;
  float4 v = *(const float4*)(x + i);
  bf16x4 o;
  o.x = (bf16)v.x; o.y = (bf16)v.y; o.z = (bf16)v.z; o.w = (bf16)v.w;
  *(bf16x4*)(xb + i) = o;
}

// in: fp32 [rows][cols]  ->  out: bf16 [cols][rows]
__global__ void k_transpose_bf16(const float* __restrict__ in, bf16* __restrict__ out,
                                 int rows, int cols) {
  __shared__ float t[32][33];
  int c0 = blockIdx.x * 32, r0 = blockIdx.y * 32;
  for (int i = threadIdx.y; i < 32; i += 8)
    t[i][threadIdx.x] = in[(size_t)(r0 + i) * cols + c0 + threadIdx.x];
  __syncthreads();
  for (int i = threadIdx.y; i < 32; i += 8)
    out[(size_t)(c0 + i) * rows + r0 + threadIdx.x] = (bf16)t[threadIdx.x][i];
}

// ---------------- QKV GEMM with fused bias + RoPE + head split ----------------
// A [4096][1024] bf16, Bt [3072][1024] bf16.  C = A*B + bias, then RoPE on Q/K
// regions (pairs (i, i+32) within each 64-dim head = acc frags n and n+2), and
// scatter to Q/K/V [32][2048][64].  Q pre-scaled by (1/8)*log2(e).

__global__ __launch_bounds__(256)
void k_gemm_qkv(const bf16* __restrict__ A, const bf16* __restrict__ Bt,
                const float* __restrict__ bias, bf16* __restrict__ Qd,
                bf16* __restrict__ Kd, bf16* __restrict__ Vd) {
  alignas(16) __shared__ bf16 lds_a[128 * 32];
  alignas(16) __shared__ bf16 lds_b[128 * 32];
  const int tid = threadIdx.x;
  const int lane = tid & 63, w = tid >> 6;
  const int wr = w >> 1, wc = w & 1;
  const int br = blockIdx.x / 24, bc = blockIdx.x % 24;
  const int r16 = lane & 15, g4 = lane >> 4;

  f32x4 acc[4][4] = {};
  const bf16* gA = A + (size_t)(br * 128 + (lane >> 2)) * 1024 + (lane & 3) * 8;
  const bf16* gB = Bt + (size_t)(bc * 128 + (lane >> 2)) * 1024 + (lane & 3) * 8;

  for (int kt = 0; kt < 32; ++kt) {
    const int ko = kt * 32;
#pragma unroll
    for (int it = 0; it < 2; ++it) {
      const int row0 = 16 * (4 * it + w);           // wave-uniform
      gload16(&lds_a[row0 * 32], gA + (size_t)row0 * 1024 + ko);
      gload16(&lds_b[row0 * 32], gB + (size_t)row0 * 1024 + ko);
    }
    __syncthreads();
    bf16x8 af[4], bfr[4];
#pragma unroll
    for (int m = 0; m < 4; ++m)
      af[m] = *(const bf16x8*)&lds_a[(wr * 64 + 16 * m + r16) * 32 + g4 * 8];
#pragma unroll
    for (int n = 0; n < 4; ++n)
      bfr[n] = *(const bf16x8*)&lds_b[(wc * 64 + 16 * n + r16) * 32 + g4 * 8];
#pragma unroll
    for (int m = 0; m < 4; ++m)
#pragma unroll
      for (int n = 0; n < 4; ++n)
        acc[m][n] = __builtin_amdgcn_mfma_f32_16x16x32_bf16(af[m], bfr[n], acc[m][n], 0, 0, 0);
    __syncthreads();
  }

  // ---- fused epilogue ----
  const int reg = bc >> 3;                       // 0=Q, 1=K, 2=V
  bf16* dst = (reg == 0) ? Qd : (reg == 1) ? Kd : Vd;
  const int h = ((bc & 7) << 1) | wc;            // head 0..15
  const float bq = 0.125f * 1.4426950408889634f; // (1/sqrt(64)) * log2(e)
  // inv_freq for i = r16 and i = 16 + r16 :  10000^(-i/32)
  const float Lc = 13.287712379549449f / 32.0f;  // log2(10000)/32
  const float if0 = exp2f(-(float)r16 * Lc);
  const float if1 = exp2f(-(float)(16 + r16) * Lc);
  float bv[4];
#pragma unroll
  for (int n = 0; n < 4; ++n) bv[n] = bias[bc * 128 + wc * 64 + 16 * n + r16];

#pragma unroll
  for (int m = 0; m < 4; ++m) {
#pragma unroll
    for (int r = 0; r < 4; ++r) {
      const int row = br * 128 + wr * 64 + 16 * m + 4 * g4 + r;
      const int t = row & 2047, b = row >> 11;
      bf16* o = dst + ((size_t)(b * 16 + h) * 2048 + t) * 64;
      const float v0 = acc[0][0][0] * 0.f + acc[m][0][r] + bv[0];
      const float v1 = acc[m][1][r] + bv[1];
      const float v2 = acc[m][2][r] + bv[2];
      const float v3 = acc[m][3][r] + bv[3];
      if (reg == 2) {
        o[r16]      = (bf16)v0;
        o[16 + r16] = (bf16)v1;
        o[32 + r16] = (bf16)v2;
        o[48 + r16] = (bf16)v3;
      } else {
        float s0, c0, s1, c1;
        const float tf = (float)t;
        sincosf(tf * if0, &s0, &c0);
        sincosf(tf * if1, &s1, &c1);
        float r0 = v0 * c0 - v2 * s0, r2 = v0 * s0 + v2 * c0;
        float r1 = v1 * c1 - v3 * s1, r3 = v1 * s1 + v3 * c1;
        if (reg == 0) { r0 *= bq; r1 *= bq; r2 *= bq; r3 *= bq; }
        o[r16]      = (bf16)r0;
        o[16 + r16] = (bf16)r1;
        o[32 + r16] = (bf16)r2;
        o[48 + r16] = (bf16)r3;
      }
    }
  }
}

// ---------------- out GEMM (m97-style 128x128, BK=32) ----------------
// A [M][K] bf16 row-major, Bt [N][K] bf16 row-major, C = A*B + bias (fp32 out).

__global__ __launch_bounds__(256)
void k_gemm_out(const bf16* __restrict__ A, const bf16* __restrict__ Bt,
                const float* __restrict__ bias, float* __restrict__ Cp,
                int M, int N, int K) {
  alignas(16) __shared__ bf16 lds_a[128 * 32];
  alignas(16) __shared__ bf16 lds_b[128 * 32];
  const int tid = threadIdx.x;
  const int lane = tid & 63, w = tid >> 6;
  const int wr = w >> 1, wc = w & 1;
  const int nb = N >> 7;
  const int br = blockIdx.x / nb, bc = blockIdx.x % nb;
  const int r16 = lane & 15, g4 = lane >> 4;

  f32x4 acc[4][4] = {};
  const int nk = K >> 5;
  const bf16* gA = A + (size_t)(br * 128 + (lane >> 2)) * K + (lane & 3) * 8;
  const bf16* gB = Bt + (size_t)(bc * 128 + (lane >> 2)) * K + (lane & 3) * 8;

  for (int kt = 0; kt < nk; ++kt) {
    const int ko = kt * 32;
#pragma unroll
    for (int it = 0; it < 2; ++it) {
      const int row0 = 16 * (4 * it + w);           // wave-uniform
      gload16(&lds_a[row0 * 32], gA + (size_t)row0 * K + ko);
      gload16(&lds_b[row0 * 32], gB + (size_t)row0 * K + ko);
    }
    __syncthreads();
    bf16x8 af[4], bfr[4];
#pragma unroll
    for (int m = 0; m < 4; ++m)
      af[m] = *(const bf16x8*)&lds_a[(wr * 64 + 16 * m + r16) * 32 + g4 * 8];
#pragma unroll
    for (int n = 0; n < 4; ++n)
      bfr[n] = *(const bf16x8*)&lds_b[(wc * 64 + 16 * n + r16) * 32 + g4 * 8];
#pragma unroll
    for (int m = 0; m < 4; ++m)
#pragma unroll
      for (int n = 0; n < 4; ++n)
        acc[m][n] = __builtin_amdgcn_mfma_f32_16x16x32_bf16(af[m], bfr[n], acc[m][n], 0, 0, 0);
    __syncthreads();
  }

#pragma unroll
  for (int m = 0; m < 4; ++m) {
    const int row = br * 128 + wr * 64 + 16 * m + 4 * g4;
#pragma unroll
    for (int n = 0; n < 4; ++n) {
      const int col = bc * 128 + wc * 64 + 16 * n + r16;
      const float bvv = bias[col];
#pragma unroll
      for (int r = 0; r < 4; ++r)
        Cp[(size_t)(row + r) * N + col] = acc[m][n][r] + bvv;
    }
  }
}

// ---------------- flash attention ----------------
// grid (T/64, B*H), 256 threads (4 waves x 16 q-rows). Online softmax in exp2 domain.

__global__ __launch_bounds__(256)
void k_attn(const bf16* __restrict__ Qg, const bf16* __restrict__ Kg,
            const bf16* __restrict__ Vg, bf16* __restrict__ Og) {
  alignas(16) __shared__ bf16 kt_lds[64][72];      // [key][d], +8 pad (2-way bank, free)
  alignas(16) __shared__ bf16 vt_lds[64][72];      // [d][key] (V transposed)
  alignas(16) __shared__ bf16 p_lds[4][16][72];    // per-wave P tile
  const int tid = threadIdx.x, lane = tid & 63, w = tid >> 6;
  const int bh = blockIdx.y, q0 = blockIdx.x * 64;
  const int r16 = lane & 15, g4 = lane >> 4;
  const bf16* Qb = Qg + (size_t)bh * 2048 * 64;
  const bf16* Kb = Kg + (size_t)bh * 2048 * 64;
  const bf16* Vb = Vg + (size_t)bh * 2048 * 64;

  bf16x8 qf[2];
  {
    const int qrow = q0 + 16 * w + r16;
    qf[0] = *(const bf16x8*)(Qb + (size_t)qrow * 64 + g4 * 8);
    qf[1] = *(const bf16x8*)(Qb + (size_t)qrow * 64 + 32 + g4 * 8);
  }

  f32x4 O[4] = {};
  float mrun[4], lrun[4];
#pragma unroll
  for (int r = 0; r < 4; ++r) { mrun[r] = -1e30f; lrun[r] = 0.f; }

  // staging: 64 rows x 64 d = 8KB per tile; 256 threads x 2 chunks x 16B
  const int srow = tid >> 2, sseg = tid & 3;
#pragma unroll 1
  for (int kt0 = 0; kt0 < 2048; kt0 += 64) {
    // stage K tile (both 32-col halves) and transposed V tile
    bf16x8 kv0 = *(const bf16x8*)(Kb + (size_t)(kt0 + srow) * 64 + sseg * 8);
    bf16x8 kv1 = *(const bf16x8*)(Kb + (size_t)(kt0 + srow) * 64 + 32 + sseg * 8);
    *(bf16x8*)&kt_lds[srow][sseg * 8] = kv0;
    *(bf16x8*)&kt_lds[srow][32 + sseg * 8] = kv1;
    bf16x8 vv0 = *(const bf16x8*)(Vb + (size_t)(kt0 + srow) * 64 + sseg * 8);
    bf16x8 vv1 = *(const bf16x8*)(Vb + (size_t)(kt0 + srow) * 64 + 32 + sseg * 8);
#pragma unroll
    for (int j = 0; j < 8; ++j) {
      vt_lds[sseg * 8 + j][srow] = vv0[j];
      vt_lds[32 + sseg * 8 + j][srow] = vv1[j];
    }
    __syncthreads();

    // S = Q K^T  (16 q-rows x 64 keys per wave)
    f32x4 S[4];
#pragma unroll
    for (int n = 0; n < 4; ++n) {
      bf16x8 kb0 = *(const bf16x8*)&kt_lds[16 * n + r16][g4 * 8];
      bf16x8 kb1 = *(const bf16x8*)&kt_lds[16 * n + r16][32 + g4 * 8];
      f32x4 s = {};
      s = __builtin_amdgcn_mfma_f32_16x16x32_bf16(qf[0], kb0, s, 0, 0, 0);
      s = __builtin_amdgcn_mfma_f32_16x16x32_bf16(qf[1], kb1, s, 0, 0, 0);
      S[n] = s;
    }

    // online softmax (rows = 4*g4 + r, cols across n and lane&15)
#pragma unroll
    for (int r = 0; r < 4; ++r) {
      float mt = fmaxf(fmaxf(S[0][r], S[1][r]), fmaxf(S[2][r], S[3][r]));
#pragma unroll
      for (int sh = 1; sh < 16; sh <<= 1) mt = fmaxf(mt, __shfl_xor(mt, sh, 64));
      const float mn = fmaxf(mrun[r], mt);
      const float alpha = exp2f(mrun[r] - mn);
      mrun[r] = mn;
      float rs = 0.f;
#pragma unroll
      for (int n = 0; n < 4; ++n) { float p = exp2f(S[n][r] - mn); S[n][r] = p; rs += p; }
#pragma unroll
      for (int sh = 1; sh < 16; sh <<= 1) rs += __shfl_xor(rs, sh, 64);
      lrun[r] = lrun[r] * alpha + rs;
#pragma unroll
      for (int n = 0; n < 4; ++n) O[n][r] *= alpha;
    }

    // P (C-layout) -> LDS -> A-layout fragments
#pragma unroll
    for (int n = 0; n < 4; ++n)
#pragma unroll
      for (int r = 0; r < 4; ++r)
        p_lds[w][4 * g4 + r][16 * n + r16] = (bf16)S[n][r];
    bf16x8 pf0 = *(const bf16x8*)&p_lds[w][r16][g4 * 8];
    bf16x8 pf1 = *(const bf16x8*)&p_lds[w][r16][32 + g4 * 8];

#pragma unroll
    for (int n = 0; n < 4; ++n) {
      bf16x8 vb0 = *(const bf16x8*)&vt_lds[16 * n + r16][g4 * 8];
      bf16x8 vb1 = *(const bf16x8*)&vt_lds[16 * n + r16][32 + g4 * 8];
      O[n] = __builtin_amdgcn_mfma_f32_16x16x32_bf16(pf0, vb0, O[n], 0, 0, 0);
      O[n] = __builtin_amdgcn_mfma_f32_16x16x32_bf16(pf1, vb1, O[n], 0, 0, 0);
    }
    __syncthreads();
  }

  // epilogue: normalize, write attn in (b, t, h*64+d) layout
  const int b = bh >> 4, h = bh & 15;
#pragma unroll
  for (int r = 0; r < 4; ++r) {
    const float inv = 1.f / lrun[r];
    const int t = q0 + 16 * w + 4 * g4 + r;
#pragma unroll
    for (int n = 0; n < 4; ++n)
      Og[((size_t)(b * 2048 + t)) * 1024 + h * 64 + 16 * n + r16] = (bf16)(O[n][r] * inv);
  }
}

// ---------------- launch ----------------

extern "C" void kernel_launch(void* const* d_in, const int* in_sizes, int n_in,
                              void* d_out, int out_size, void* d_ws, size_t ws_size,
                              hipStream_t stream) {
  const float* x     = (const float*)d_in[0];
  const float* w_qkv = (const float*)d_in[1];
  const float* b_qkv = (const float*)d_in[2];
  const float* w_out = (const float*)d_in[3];
  const float* b_out = (const float*)d_in[4];
  float* out = (float*)d_out;

  char* ws = (char*)d_ws;
  bf16* xb    = (bf16*)(ws);
  bf16* wqkvT = (bf16*)(ws + 8388608);
  bf16* woutT = (bf16*)(ws + 14680064);
  bf16* Qb    = (bf16*)(ws + 16777216);
  bf16* Kb    = (bf16*)(ws + 25165824);
  bf16* Vb    = (bf16*)(ws + 33554432);
  bf16* attnb = (bf16*)(ws + 41943040);

  k_convert_x<<<4096 * 1024 / 4 / 256, 256, 0, stream>>>(x, xb, 4096 * 1024);
  k_transpose_bf16<<<dim3(3072 / 32, 1024 / 32), dim3(32, 8), 0, stream>>>(w_qkv, wqkvT, 1024, 3072);
  k_transpose_bf16<<<dim3(1024 / 32, 1024 / 32), dim3(32, 8), 0, stream>>>(w_out, woutT, 1024, 1024);
  k_gemm_qkv<<<32 * 24, 256, 0, stream>>>(xb, wqkvT, b_qkv, Qb, Kb, Vb);
  k_attn<<<dim3(32, 32), 256, 0, stream>>>(Qb, Kb, Vb, attnb);
  k_gemm_out<<<32 * 8, 256, 0, stream>>>(attnb, woutT, b_out, out, 4096, 1024, 1024);
}

// Round 4
// 198.186 us; speedup vs baseline: 1.1600x; 1.1600x over previous
//
#include <hip/hip_runtime.h>
#include <hip/hip_bf16.h>
#include <stdint.h>

// Problem: B=2, T=2048, D=1024, H=16, hd=64.  M = B*T = 4096.
// Pipeline: x->bf16 ; w^T->bf16 ; QKV gemm w/ fused bias+RoPE+head-split ; flash attn ; out gemm.
// Workspace layout (bytes), total 50,331,648 (48 MiB -- must stay < 64 MiB, see R2 post-mortem):
//   0        x_bf16   [4096][1024]
//   8388608  wqkvT    [3072][1024]
//   14680064 woutT    [1024][1024]
//   16777216 Q        [32][2048][64]   (pre-scaled by log2e/8, RoPE'd)
//   25165824 K        [32][2048][64]   (RoPE'd)
//   33554432 V^T      [32][64][2048]   (transposed at producer!)
//   41943040 attn     [4096][1024]

typedef __bf16 bf16;
typedef __bf16 bf16x8 __attribute__((ext_vector_type(8)));
typedef __bf16 bf16x4 __attribute__((ext_vector_type(4)));
typedef float  f32x4  __attribute__((ext_vector_type(4)));

__device__ __forceinline__ void gload16(void* lds, const void* g) {
  // async global->LDS, 16B per lane, dest = wave-uniform base + lane*16
  __builtin_amdgcn_global_load_lds((__attribute__((address_space(1))) void*)(void*)g,
                                   (__attribute__((address_space(3))) void*)lds, 16, 0, 0);
}

// ---------------- conversion kernels ----------------

__global__ void k_convert_x(const float* __restrict__ x, bf16* __restrict__ xb, int n) {
  int i = (blockIdx.x * blockDim.x + threadIdx.x) * 4;
  if (i >= n) return;
  float4 v = *(const float4*)(x + i);
  bf16x4 o;
  o.x = (bf16)v.x; o.y = (bf16)v.y; o.z = (bf16)v.z; o.w = (bf16)v.w;
  *(bf16x4*)(xb + i) = o;
}

// in: fp32 [rows][cols]  ->  out: bf16 [cols][rows]
__global__ void k_transpose_bf16(const float* __restrict__ in, bf16* __restrict__ out,
                                 int rows, int cols) {
  __shared__ float t[32][33];
  int c0 = blockIdx.x * 32, r0 = blockIdx.y * 32;
  for (int i = threadIdx.y; i < 32; i += 8)
    t[i][threadIdx.x] = in[(size_t)(r0 + i) * cols + c0 + threadIdx.x];
  __syncthreads();
  for (int i = threadIdx.y; i < 32; i += 8)
    out[(size_t)(c0 + i) * rows + r0 + threadIdx.x] = (bf16)t[threadIdx.x][i];
}

// ---------------- QKV GEMM with fused bias + RoPE + head split ----------------
// A [4096][1024] bf16, Bt [3072][1024] bf16.  C = A*B + bias, then RoPE on Q/K
// (pairs (i, i+32) within each 64-dim head = acc frags n and n+2), scatter to
// Q/K [32][2048][64] and V^T [32][64][2048].  Q pre-scaled by (1/8)*log2(e).

__global__ __launch_bounds__(256)
void k_gemm_qkv(const bf16* __restrict__ A, const bf16* __restrict__ Bt,
                const float* __restrict__ bias, bf16* __restrict__ Qd,
                bf16* __restrict__ Kd, bf16* __restrict__ Vtd) {
  alignas(16) __shared__ bf16 lds_a[128 * 32];
  alignas(16) __shared__ bf16 lds_b[128 * 32];
  const int tid = threadIdx.x;
  const int lane = tid & 63, w = tid >> 6;
  const int wr = w >> 1, wc = w & 1;
  const int br = blockIdx.x / 24, bc = blockIdx.x % 24;
  const int r16 = lane & 15, g4 = lane >> 4;

  f32x4 acc[4][4] = {};
  const bf16* gA = A + (size_t)(br * 128 + (lane >> 2)) * 1024 + (lane & 3) * 8;
  const bf16* gB = Bt + (size_t)(bc * 128 + (lane >> 2)) * 1024 + (lane & 3) * 8;

  for (int kt = 0; kt < 32; ++kt) {
    const int ko = kt * 32;
#pragma unroll
    for (int it = 0; it < 2; ++it) {
      const int row0 = 16 * (4 * it + w);           // wave-uniform
      gload16(&lds_a[row0 * 32], gA + (size_t)row0 * 1024 + ko);
      gload16(&lds_b[row0 * 32], gB + (size_t)row0 * 1024 + ko);
    }
    __syncthreads();
    bf16x8 af[4], bfr[4];
#pragma unroll
    for (int m = 0; m < 4; ++m)
      af[m] = *(const bf16x8*)&lds_a[(wr * 64 + 16 * m + r16) * 32 + g4 * 8];
#pragma unroll
    for (int n = 0; n < 4; ++n)
      bfr[n] = *(const bf16x8*)&lds_b[(wc * 64 + 16 * n + r16) * 32 + g4 * 8];
#pragma unroll
    for (int m = 0; m < 4; ++m)
#pragma unroll
      for (int n = 0; n < 4; ++n)
        acc[m][n] = __builtin_amdgcn_mfma_f32_16x16x32_bf16(af[m], bfr[n], acc[m][n], 0, 0, 0);
    __syncthreads();
  }

  // ---- fused epilogue ----
  const int reg = bc >> 3;                       // 0=Q, 1=K, 2=V
  const int h = ((bc & 7) << 1) | wc;            // head 0..15
  const float bq = 0.125f * 1.4426950408889634f; // (1/sqrt(64)) * log2(e)
  const float Lc = 13.287712379549449f / 32.0f;  // log2(10000)/32
  const float if0 = exp2f(-(float)r16 * Lc);
  const float if1 = exp2f(-(float)(16 + r16) * Lc);
  float bv[4];
#pragma unroll
  for (int n = 0; n < 4; ++n) bv[n] = bias[bc * 128 + wc * 64 + 16 * n + r16];

  if (reg == 2) {
    // V: write transposed layout V^T[b*16+h][d][t], vectorized bf16x4 over t
#pragma unroll
    for (int m = 0; m < 4; ++m) {
      const int row0 = br * 128 + wr * 64 + 16 * m + 4 * g4;
      const int t0 = row0 & 2047, b = row0 >> 11;
#pragma unroll
      for (int n = 0; n < 4; ++n) {
        bf16x4 pk;
#pragma unroll
        for (int r = 0; r < 4; ++r) pk[r] = (bf16)(acc[m][n][r] + bv[n]);
        *(bf16x4*)(Vtd + ((size_t)((b * 16 + h) * 64) + 16 * n + r16) * 2048 + t0) = pk;
      }
    }
  } else {
    bf16* dst = (reg == 0) ? Qd : Kd;
#pragma unroll
    for (int m = 0; m < 4; ++m) {
#pragma unroll
      for (int r = 0; r < 4; ++r) {
        const int row = br * 128 + wr * 64 + 16 * m + 4 * g4 + r;
        const int t = row & 2047, b = row >> 11;
        bf16* o = dst + ((size_t)(b * 16 + h) * 2048 + t) * 64;
        const float v0 = acc[m][0][r] + bv[0];
        const float v1 = acc[m][1][r] + bv[1];
        const float v2 = acc[m][2][r] + bv[2];
        const float v3 = acc[m][3][r] + bv[3];
        float s0, c0, s1, c1;
        const float tf = (float)t;
        sincosf(tf * if0, &s0, &c0);
        sincosf(tf * if1, &s1, &c1);
        float r0 = v0 * c0 - v2 * s0, r2 = v0 * s0 + v2 * c0;
        float r1 = v1 * c1 - v3 * s1, r3 = v1 * s1 + v3 * c1;
        if (reg == 0) { r0 *= bq; r1 *= bq; r2 *= bq; r3 *= bq; }
        o[r16]      = (bf16)r0;
        o[16 + r16] = (bf16)r1;
        o[32 + r16] = (bf16)r2;
        o[48 + r16] = (bf16)r3;
      }
    }
  }
}

// ---------------- out GEMM (m97-style 128x128, BK=32) ----------------

__global__ __launch_bounds__(256)
void k_gemm_out(const bf16* __restrict__ A, const bf16* __restrict__ Bt,
                const float* __restrict__ bias, float* __restrict__ Cp,
                int M, int N, int K) {
  alignas(16) __shared__ bf16 lds_a[128 * 32];
  alignas(16) __shared__ bf16 lds_b[128 * 32];
  const int tid = threadIdx.x;
  const int lane = tid & 63, w = tid >> 6;
  const int wr = w >> 1, wc = w & 1;
  const int nb = N >> 7;
  const int br = blockIdx.x / nb, bc = blockIdx.x % nb;
  const int r16 = lane & 15, g4 = lane >> 4;

  f32x4 acc[4][4] = {};
  const int nk = K >> 5;
  const bf16* gA = A + (size_t)(br * 128 + (lane >> 2)) * K + (lane & 3) * 8;
  const bf16* gB = Bt + (size_t)(bc * 128 + (lane >> 2)) * K + (lane & 3) * 8;

  for (int kt = 0; kt < nk; ++kt) {
    const int ko = kt * 32;
#pragma unroll
    for (int it = 0; it < 2; ++it) {
      const int row0 = 16 * (4 * it + w);           // wave-uniform
      gload16(&lds_a[row0 * 32], gA + (size_t)row0 * K + ko);
      gload16(&lds_b[row0 * 32], gB + (size_t)row0 * K + ko);
    }
    __syncthreads();
    bf16x8 af[4], bfr[4];
#pragma unroll
    for (int m = 0; m < 4; ++m)
      af[m] = *(const bf16x8*)&lds_a[(wr * 64 + 16 * m + r16) * 32 + g4 * 8];
#pragma unroll
    for (int n = 0; n < 4; ++n)
      bfr[n] = *(const bf16x8*)&lds_b[(wc * 64 + 16 * n + r16) * 32 + g4 * 8];
#pragma unroll
    for (int m = 0; m < 4; ++m)
#pragma unroll
      for (int n = 0; n < 4; ++n)
        acc[m][n] = __builtin_amdgcn_mfma_f32_16x16x32_bf16(af[m], bfr[n], acc[m][n], 0, 0, 0);
    __syncthreads();
  }

#pragma unroll
  for (int m = 0; m < 4; ++m) {
    const int row = br * 128 + wr * 64 + 16 * m + 4 * g4;
#pragma unroll
    for (int n = 0; n < 4; ++n) {
      const int col = bc * 128 + wc * 64 + 16 * n + r16;
      const float bvv = bias[col];
#pragma unroll
      for (int r = 0; r < 4; ++r)
        Cp[(size_t)(row + r) * N + col] = acc[m][n][r] + bvv;
    }
  }
}

// ---------------- flash attention ----------------
// grid (T/64, B*H), 256 threads (4 waves x 16 q-rows).
// K and V^T staged via global_load_lds (linear dest, pre-swizzled source,
// XOR-swizzled reads: byte ^= (row&7)<<4), double-buffered.

__global__ __launch_bounds__(256)
void k_attn(const bf16* __restrict__ Qg, const bf16* __restrict__ Kg,
            const bf16* __restrict__ Vtg, bf16* __restrict__ Og) {
  alignas(16) __shared__ bf16 kbuf[2][4096];   // [key 64][d 64] swizzled
  alignas(16) __shared__ bf16 vbuf[2][4096];   // [d 64][key 64] swizzled (from V^T)
  alignas(16) __shared__ bf16 pbuf[4][1024];   // per-wave [q 16][key 64] swizzled
  const int tid = threadIdx.x, lane = tid & 63, w = tid >> 6;
  const int bh = blockIdx.y, q0 = blockIdx.x * 64;
  const int r16 = lane & 15, g4 = lane >> 4;
  const char* Kb  = (const char*)(Kg  + (size_t)bh * 2048 * 64);
  const char* Vtb = (const char*)(Vtg + (size_t)bh * 64 * 2048);
  const bf16* Qb  = Qg + (size_t)bh * 2048 * 64;

  // staging geometry: per wave 2 chunks of 1KB each for K and V^T.
  // chunk (2w+c) covers rows 16w+8c .. +7 ; lane covers row rl=lane>>3,
  // 16B at swizzled col ((lane&7)*16) ^ (rl<<4).
  const int rl = lane >> 3;
  const int colx = ((lane & 7) * 16) ^ (rl << 4);

  bf16x8 qf[2];
  {
    const int qrow = q0 + 16 * w + r16;
    qf[0] = *(const bf16x8*)(Qb + (size_t)qrow * 64 + g4 * 8);
    qf[1] = *(const bf16x8*)(Qb + (size_t)qrow * 64 + 32 + g4 * 8);
  }

  f32x4 O[4] = {};
  float mrun[4], lrun[4];
#pragma unroll
  for (int r = 0; r < 4; ++r) { mrun[r] = -1e30f; lrun[r] = 0.f; }

#define STAGE(bufi, t0)                                                          \
  {                                                                              \
    _Pragma("unroll")                                                            \
    for (int c = 0; c < 2; ++c) {                                                \
      const int row = 16 * w + 8 * c + rl;                                       \
      gload16(&kbuf[bufi][(2 * w + c) * 512],                                    \
              Kb + (size_t)((t0) + row) * 128 + colx);                           \
      gload16(&vbuf[bufi][(2 * w + c) * 512],                                    \
              Vtb + (size_t)row * 4096 + (size_t)(t0) * 2 + colx);               \
    }                                                                            \
  }

  STAGE(0, 0);
  __syncthreads();

  const int rsw = (r16 & 7) << 4;           // read-side swizzle for rows r16-based
  const char* pw = (const char*)pbuf[w];

#pragma unroll 1
  for (int it = 0; it < 32; ++it) {
    const int bsel = it & 1;
    if (it + 1 < 32) STAGE(bsel ^ 1, (it + 1) * 64);
    const char* kb = (const char*)kbuf[bsel];
    const char* vb = (const char*)vbuf[bsel];

    // S = Q K^T  (16 q-rows x 64 keys per wave)
    f32x4 S[4];
#pragma unroll
    for (int n = 0; n < 4; ++n) {
      bf16x8 kb0 = *(const bf16x8*)(kb + (16 * n + r16) * 128 + ((g4 * 16) ^ rsw));
      bf16x8 kb1 = *(const bf16x8*)(kb + (16 * n + r16) * 128 + ((64 + g4 * 16) ^ rsw));
      f32x4 s = {};
      s = __builtin_amdgcn_mfma_f32_16x16x32_bf16(qf[0], kb0, s, 0, 0, 0);
      s = __builtin_amdgcn_mfma_f32_16x16x32_bf16(qf[1], kb1, s, 0, 0, 0);
      S[n] = s;
    }

    // online softmax (rows = 4*g4 + r, cols across n and lane&15)
#pragma unroll
    for (int r = 0; r < 4; ++r) {
      float mt = fmaxf(fmaxf(S[0][r], S[1][r]), fmaxf(S[2][r], S[3][r]));
#pragma unroll
      for (int sh = 1; sh < 16; sh <<= 1) mt = fmaxf(mt, __shfl_xor(mt, sh, 64));
      const float mn = fmaxf(mrun[r], mt);
      const float alpha = exp2f(mrun[r] - mn);
      mrun[r] = mn;
      float rs = 0.f;
#pragma unroll
      for (int n = 0; n < 4; ++n) { float p = exp2f(S[n][r] - mn); S[n][r] = p; rs += p; }
#pragma unroll
      for (int sh = 1; sh < 16; sh <<= 1) rs += __shfl_xor(rs, sh, 64);
      lrun[r] = lrun[r] * alpha + rs;
#pragma unroll
      for (int n = 0; n < 4; ++n) O[n][r] *= alpha;
    }

    // P (C-layout) -> per-wave LDS (swizzled rows) -> A-layout fragments
#pragma unroll
    for (int n = 0; n < 4; ++n)
#pragma unroll
      for (int r = 0; r < 4; ++r) {
        const int prow = 4 * g4 + r;
        *(bf16*)((char*)pbuf[w] + prow * 128 + (((16 * n + r16) * 2) ^ ((prow & 7) << 4))) =
            (bf16)S[n][r];
      }
    bf16x8 pf0 = *(const bf16x8*)(pw + r16 * 128 + ((g4 * 16) ^ rsw));
    bf16x8 pf1 = *(const bf16x8*)(pw + r16 * 128 + ((64 + g4 * 16) ^ rsw));

    // O += P V   (B-fragments from V^T rows = d)
#pragma unroll
    for (int n = 0; n < 4; ++n) {
      bf16x8 vb0 = *(const bf16x8*)(vb + (16 * n + r16) * 128 + ((g4 * 16) ^ rsw));
      bf16x8 vb1 = *(const bf16x8*)(vb + (16 * n + r16) * 128 + ((64 + g4 * 16) ^ rsw));
      O[n] = __builtin_amdgcn_mfma_f32_16x16x32_bf16(pf0, vb0, O[n], 0, 0, 0);
      O[n] = __builtin_amdgcn_mfma_f32_16x16x32_bf16(pf1, vb1, O[n], 0, 0, 0);
    }
    __syncthreads();
  }
#undef STAGE

  // epilogue: normalize, write attn in (b, t, h*64+d) layout
  const int b = bh >> 4, h = bh & 15;
#pragma unroll
  for (int r = 0; r < 4; ++r) {
    const float inv = 1.f / lrun[r];
    const int t = q0 + 16 * w + 4 * g4 + r;
#pragma unroll
    for (int n = 0; n < 4; ++n)
      Og[((size_t)(b * 2048 + t)) * 1024 + h * 64 + 16 * n + r16] = (bf16)(O[n][r] * inv);
  }
}

// ---------------- launch ----------------

extern "C" void kernel_launch(void* const* d_in, const int* in_sizes, int n_in,
                              void* d_out, int out_size, void* d_ws, size_t ws_size,
                              hipStream_t stream) {
  const float* x     = (const float*)d_in[0];
  const float* w_qkv = (const float*)d_in[1];
  const float* b_qkv = (const float*)d_in[2];
  const float* w_out = (const float*)d_in[3];
  const float* b_out = (const float*)d_in[4];
  float* out = (float*)d_out;

  char* ws = (char*)d_ws;
  bf16* xb    = (bf16*)(ws);
  bf16* wqkvT = (bf16*)(ws + 8388608);
  bf16* woutT = (bf16*)(ws + 14680064);
  bf16* Qb    = (bf16*)(ws + 16777216);
  bf16* Kb    = (bf16*)(ws + 25165824);
  bf16* Vtb   = (bf16*)(ws + 33554432);
  bf16* attnb = (bf16*)(ws + 41943040);

  k_convert_x<<<4096 * 1024 / 4 / 256, 256, 0, stream>>>(x, xb, 4096 * 1024);
  k_transpose_bf16<<<dim3(3072 / 32, 1024 / 32), dim3(32, 8), 0, stream>>>(w_qkv, wqkvT, 1024, 3072);
  k_transpose_bf16<<<dim3(1024 / 32, 1024 / 32), dim3(32, 8), 0, stream>>>(w_out, woutT, 1024, 1024);
  k_gemm_qkv<<<32 * 24, 256, 0, stream>>>(xb, wqkvT, b_qkv, Qb, Kb, Vtb);
  k_attn<<<dim3(32, 32), 256, 0, stream>>>(Qb, Kb, Vtb, attnb);
  k_gemm_out<<<32 * 8, 256, 0, stream>>>(attnb, woutT, b_out, out, 4096, 1024, 1024);
}

// Round 6
// 160.434 us; speedup vs baseline: 1.4330x; 1.2353x over previous
//
#include <hip/hip_runtime.h>
#include <hip/hip_bf16.h>
#include <stdint.h>

// Problem: B=2, T=2048, D=1024, H=16, hd=64.  M = B*T = 4096.
// Pipeline: x->bf16 ; w^T->bf16 ; QKV gemm w/ fused bias+RoPE+head-split ; flash attn ; out gemm.
// Workspace layout (bytes), total 50,331,648 (48 MiB -- must stay < 64 MiB, see R2 post-mortem):
//   0        x_bf16   [4096][1024]
//   8388608  wqkvT    [3072][1024]
//   14680064 woutT    [1024][1024]
//   16777216 Q        [32][2048][64]   (pre-scaled by log2e/8, RoPE'd)
//   25165824 K        [32][2048][64]   (RoPE'd)
//   33554432 V^T      [32][64][2048]   (transposed at producer)
//   41943040 attn     [4096][1024]

typedef __bf16 bf16;
typedef __bf16 bf16x8 __attribute__((ext_vector_type(8)));
typedef __bf16 bf16x4 __attribute__((ext_vector_type(4)));
typedef short  s16x4  __attribute__((ext_vector_type(4)));
typedef float  f32x4  __attribute__((ext_vector_type(4)));

__device__ __forceinline__ void gload16(void* lds, const void* g) {
  // async global->LDS, 16B per lane, dest = wave-uniform base + lane*16
  __builtin_amdgcn_global_load_lds((__attribute__((address_space(1))) void*)(void*)g,
                                   (__attribute__((address_space(3))) void*)lds, 16, 0, 0);
}

__device__ __forceinline__ f32x4 mfma16x16x16(bf16x4 a, bf16x4 b, f32x4 c) {
  return __builtin_amdgcn_mfma_f32_16x16x16bf16_1k(
      __builtin_bit_cast(s16x4, a), __builtin_bit_cast(s16x4, b), c, 0, 0, 0);
}

// ---------------- conversion kernels ----------------

__global__ void k_convert_x(const float* __restrict__ x, bf16* __restrict__ xb, int n) {
  int i = (blockIdx.x * blockDim.x + threadIdx.x) * 4;
  if (i >= n) return;
  float4 v = *(const float4*)(x + i);
  bf16x4 o;
  o.x = (bf16)v.x; o.y = (bf16)v.y; o.z = (bf16)v.z; o.w = (bf16)v.w;
  *(bf16x4*)(xb + i) = o;
}

// in: fp32 [rows][cols]  ->  out: bf16 [cols][rows]
__global__ void k_transpose_bf16(const float* __restrict__ in, bf16* __restrict__ out,
                                 int rows, int cols) {
  __shared__ float t[32][33];
  int c0 = blockIdx.x * 32, r0 = blockIdx.y * 32;
  for (int i = threadIdx.y; i < 32; i += 8)
    t[i][threadIdx.x] = in[(size_t)(r0 + i) * cols + c0 + threadIdx.x];
  __syncthreads();
  for (int i = threadIdx.y; i < 32; i += 8)
    out[(size_t)(c0 + i) * rows + r0 + threadIdx.x] = (bf16)t[threadIdx.x][i];
}

// ---------------- QKV GEMM with fused bias + RoPE + head split ----------------

__global__ __launch_bounds__(256)
void k_gemm_qkv(const bf16* __restrict__ A, const bf16* __restrict__ Bt,
                const float* __restrict__ bias, bf16* __restrict__ Qd,
                bf16* __restrict__ Kd, bf16* __restrict__ Vtd) {
  alignas(16) __shared__ bf16 lds_a[128 * 32];
  alignas(16) __shared__ bf16 lds_b[128 * 32];
  const int tid = threadIdx.x;
  const int lane = tid & 63, w = tid >> 6;
  const int wr = w >> 1, wc = w & 1;
  const int br = blockIdx.x / 24, bc = blockIdx.x % 24;
  const int r16 = lane & 15, g4 = lane >> 4;

  f32x4 acc[4][4] = {};
  const bf16* gA = A + (size_t)(br * 128 + (lane >> 2)) * 1024 + (lane & 3) * 8;
  const bf16* gB = Bt + (size_t)(bc * 128 + (lane >> 2)) * 1024 + (lane & 3) * 8;

  for (int kt = 0; kt < 32; ++kt) {
    const int ko = kt * 32;
#pragma unroll
    for (int it = 0; it < 2; ++it) {
      const int row0 = 16 * (4 * it + w);           // wave-uniform
      gload16(&lds_a[row0 * 32], gA + (size_t)row0 * 1024 + ko);
      gload16(&lds_b[row0 * 32], gB + (size_t)row0 * 1024 + ko);
    }
    __syncthreads();
    bf16x8 af[4], bfr[4];
#pragma unroll
    for (int m = 0; m < 4; ++m)
      af[m] = *(const bf16x8*)&lds_a[(wr * 64 + 16 * m + r16) * 32 + g4 * 8];
#pragma unroll
    for (int n = 0; n < 4; ++n)
      bfr[n] = *(const bf16x8*)&lds_b[(wc * 64 + 16 * n + r16) * 32 + g4 * 8];
#pragma unroll
    for (int m = 0; m < 4; ++m)
#pragma unroll
      for (int n = 0; n < 4; ++n)
        acc[m][n] = __builtin_amdgcn_mfma_f32_16x16x32_bf16(af[m], bfr[n], acc[m][n], 0, 0, 0);
    __syncthreads();
  }

  // ---- fused epilogue ----
  const int reg = bc >> 3;                       // 0=Q, 1=K, 2=V
  const int h = ((bc & 7) << 1) | wc;            // head 0..15
  const float bq = 0.125f * 1.4426950408889634f; // (1/sqrt(64)) * log2(e)
  const float Lc = 13.287712379549449f / 32.0f;  // log2(10000)/32
  const float if0 = exp2f(-(float)r16 * Lc);
  const float if1 = exp2f(-(float)(16 + r16) * Lc);
  float bv[4];
#pragma unroll
  for (int n = 0; n < 4; ++n) bv[n] = bias[bc * 128 + wc * 64 + 16 * n + r16];

  if (reg == 2) {
    // V: write transposed layout V^T[b*16+h][d][t], vectorized bf16x4 over t
#pragma unroll
    for (int m = 0; m < 4; ++m) {
      const int row0 = br * 128 + wr * 64 + 16 * m + 4 * g4;
      const int t0 = row0 & 2047, b = row0 >> 11;
#pragma unroll
      for (int n = 0; n < 4; ++n) {
        bf16x4 pk;
#pragma unroll
        for (int r = 0; r < 4; ++r) pk[r] = (bf16)(acc[m][n][r] + bv[n]);
        *(bf16x4*)(Vtd + ((size_t)((b * 16 + h) * 64) + 16 * n + r16) * 2048 + t0) = pk;
      }
    }
  } else {
    bf16* dst = (reg == 0) ? Qd : Kd;
#pragma unroll
    for (int m = 0; m < 4; ++m) {
#pragma unroll
      for (int r = 0; r < 4; ++r) {
        const int row = br * 128 + wr * 64 + 16 * m + 4 * g4 + r;
        const int t = row & 2047, b = row >> 11;
        bf16* o = dst + ((size_t)(b * 16 + h) * 2048 + t) * 64;
        const float v0 = acc[m][0][r] + bv[0];
        const float v1 = acc[m][1][r] + bv[1];
        const float v2 = acc[m][2][r] + bv[2];
        const float v3 = acc[m][3][r] + bv[3];
        float s0, c0, s1, c1;
        const float tf = (float)t;
        sincosf(tf * if0, &s0, &c0);
        sincosf(tf * if1, &s1, &c1);
        float r0 = v0 * c0 - v2 * s0, r2 = v0 * s0 + v2 * c0;
        float r1 = v1 * c1 - v3 * s1, r3 = v1 * s1 + v3 * c1;
        if (reg == 0) { r0 *= bq; r1 *= bq; r2 *= bq; r3 *= bq; }
        o[r16]      = (bf16)r0;
        o[16 + r16] = (bf16)r1;
        o[32 + r16] = (bf16)r2;
        o[48 + r16] = (bf16)r3;
      }
    }
  }
}

// ---------------- out GEMM (m97-style 128x128, BK=32) ----------------

__global__ __launch_bounds__(256)
void k_gemm_out(const bf16* __restrict__ A, const bf16* __restrict__ Bt,
                const float* __restrict__ bias, float* __restrict__ Cp,
                int M, int N, int K) {
  alignas(16) __shared__ bf16 lds_a[128 * 32];
  alignas(16) __shared__ bf16 lds_b[128 * 32];
  const int tid = threadIdx.x;
  const int lane = tid & 63, w = tid >> 6;
  const int wr = w >> 1, wc = w & 1;
  const int nb = N >> 7;
  const int br = blockIdx.x / nb, bc = blockIdx.x % nb;
  const int r16 = lane & 15, g4 = lane >> 4;

  f32x4 acc[4][4] = {};
  const int nk = K >> 5;
  const bf16* gA = A + (size_t)(br * 128 + (lane >> 2)) * K + (lane & 3) * 8;
  const bf16* gB = Bt + (size_t)(bc * 128 + (lane >> 2)) * K + (lane & 3) * 8;

  for (int kt = 0; kt < nk; ++kt) {
    const int ko = kt * 32;
#pragma unroll
    for (int it = 0; it < 2; ++it) {
      const int row0 = 16 * (4 * it + w);           // wave-uniform
      gload16(&lds_a[row0 * 32], gA + (size_t)row0 * K + ko);
      gload16(&lds_b[row0 * 32], gB + (size_t)row0 * K + ko);
    }
    __syncthreads();
    bf16x8 af[4], bfr[4];
#pragma unroll
    for (int m = 0; m < 4; ++m)
      af[m] = *(const bf16x8*)&lds_a[(wr * 64 + 16 * m + r16) * 32 + g4 * 8];
#pragma unroll
    for (int n = 0; n < 4; ++n)
      bfr[n] = *(const bf16x8*)&lds_b[(wc * 64 + 16 * n + r16) * 32 + g4 * 8];
#pragma unroll
    for (int m = 0; m < 4; ++m)
#pragma unroll
      for (int n = 0; n < 4; ++n)
        acc[m][n] = __builtin_amdgcn_mfma_f32_16x16x32_bf16(af[m], bfr[n], acc[m][n], 0, 0, 0);
    __syncthreads();
  }

#pragma unroll
  for (int m = 0; m < 4; ++m) {
    const int row = br * 128 + wr * 64 + 16 * m + 4 * g4;
#pragma unroll
    for (int n = 0; n < 4; ++n) {
      const int col = bc * 128 + wc * 64 + 16 * n + r16;
      const float bvv = bias[col];
#pragma unroll
      for (int r = 0; r < 4; ++r)
        Cp[(size_t)(row + r) * N + col] = acc[m][n][r] + bvv;
    }
  }
}

// ---------------- flash attention ----------------
// grid (T/64, B*H), 256 threads (4 waves x 16 q-rows).
// Swapped QK^T: S^T = mfma(K,Q) -> lane owns 16 k-scores for ONE q row
// (q = lane&15); softmax is in-lane; P^T register fragments feed PV
// (16x16x16 mfma) directly -> no P LDS round-trip.  Defer-max (THR=8).
// PV: O^T[dsub] accumulates over ALL four key-subtiles (double loop --
// R5 bug was single-loop conflating d-subtile with key-subtile).

__global__ __launch_bounds__(256)
void k_attn(const bf16* __restrict__ Qg, const bf16* __restrict__ Kg,
            const bf16* __restrict__ Vtg, bf16* __restrict__ Og) {
  alignas(16) __shared__ bf16 kbuf[2][4096];   // [key 64][d 64] swizzled
  alignas(16) __shared__ bf16 vbuf[2][4096];   // [d 64][key 64] swizzled (from V^T)
  const int tid = threadIdx.x, lane = tid & 63, w = tid >> 6;
  const int bh = blockIdx.y, q0 = blockIdx.x * 64;
  const int r16 = lane & 15, g4 = lane >> 4;
  const char* Kb  = (const char*)(Kg  + (size_t)bh * 2048 * 64);
  const char* Vtb = (const char*)(Vtg + (size_t)bh * 64 * 2048);
  const bf16* Qb  = Qg + (size_t)bh * 2048 * 64;

  // staging geometry: per wave 2 chunks of 1KB each for K and V^T.
  const int rl = lane >> 3;
  const int colx = ((lane & 7) * 16) ^ (rl << 4);

  bf16x8 qf[2];
  {
    const int qrow = q0 + 16 * w + r16;
    qf[0] = *(const bf16x8*)(Qb + (size_t)qrow * 64 + g4 * 8);
    qf[1] = *(const bf16x8*)(Qb + (size_t)qrow * 64 + 32 + g4 * 8);
  }

  // O^T accumulator: O[dn] holds O[q=r16][d=16*dn+4*g4+r]
  f32x4 O[4] = {};
  float m = -1e30f, lsum = 0.f;

#define STAGE(bufi, t0)                                                          \
  {                                                                              \
    _Pragma("unroll")                                                            \
    for (int c = 0; c < 2; ++c) {                                                \
      const int row = 16 * w + 8 * c + rl;                                       \
      gload16(&kbuf[bufi][(2 * w + c) * 512],                                    \
              Kb + (size_t)((t0) + row) * 128 + colx);                           \
      gload16(&vbuf[bufi][(2 * w + c) * 512],                                    \
              Vtb + (size_t)row * 4096 + (size_t)(t0) * 2 + colx);               \
    }                                                                            \
  }

  STAGE(0, 0);
  __syncthreads();

  const int rsw = (r16 & 7) << 4;           // read-side swizzle for r16-based rows

#pragma unroll 1
  for (int it = 0; it < 32; ++it) {
    const int bsel = it & 1;
    if (it + 1 < 32) STAGE(bsel ^ 1, (it + 1) * 64);
    const char* kb = (const char*)kbuf[bsel];
    const char* vb = (const char*)vbuf[bsel];

    // S^T = K Q^T : lane holds S^T[key=16n+4g4+r][q=r16]
    f32x4 S[4];
#pragma unroll
    for (int n = 0; n < 4; ++n) {
      bf16x8 kb0 = *(const bf16x8*)(kb + (16 * n + r16) * 128 + ((g4 * 16) ^ rsw));
      bf16x8 kb1 = *(const bf16x8*)(kb + (16 * n + r16) * 128 + ((64 + g4 * 16) ^ rsw));
      f32x4 s = {};
      s = __builtin_amdgcn_mfma_f32_16x16x32_bf16(kb0, qf[0], s, 0, 0, 0);
      s = __builtin_amdgcn_mfma_f32_16x16x32_bf16(kb1, qf[1], s, 0, 0, 0);
      S[n] = s;
    }

    // in-lane max over this lane's 16 scores
    float pmax = fmaxf(fmaxf(fmaxf(S[0][0], S[0][1]), fmaxf(S[0][2], S[0][3])),
                       fmaxf(fmaxf(S[1][0], S[1][1]), fmaxf(S[1][2], S[1][3])));
    pmax = fmaxf(pmax,
                 fmaxf(fmaxf(fmaxf(S[2][0], S[2][1]), fmaxf(S[2][2], S[2][3])),
                       fmaxf(fmaxf(S[3][0], S[3][1]), fmaxf(S[3][2], S[3][3]))));

    // defer-max: rescale only when max grew beyond THR=8 (exp2 domain)
    if (!__all(pmax - m <= 8.0f)) {
      float gmax = pmax;
      gmax = fmaxf(gmax, __shfl_xor(gmax, 16, 64));
      gmax = fmaxf(gmax, __shfl_xor(gmax, 32, 64));
      const float mn = fmaxf(m, gmax);
      const float alpha = exp2f(m - mn);
      m = mn;
      lsum *= alpha;
#pragma unroll
      for (int n = 0; n < 4; ++n)
#pragma unroll
        for (int r = 0; r < 4; ++r) O[n][r] *= alpha;
    }

    // P = exp2(S - m); partial row-sum in-lane; P^T frags feed PV directly
    float psum = 0.f;
    bf16x4 pb[4];
#pragma unroll
    for (int n = 0; n < 4; ++n) {
#pragma unroll
      for (int r = 0; r < 4; ++r) {
        const float p = exp2f(S[n][r] - m);
        psum += p;
        pb[n][r] = (bf16)p;
      }
    }
    lsum += psum;

    // O^T += V^T P^T : output d-subtile dn (A-row = d = 16*dn + r16),
    // accumulated over key-subtiles kn (A k-elems = keys 16*kn+4*g4+j,
    // B = pb[kn] -- P^T C-layout rows ARE the K=16 B-fragment layout).
#pragma unroll
    for (int dn = 0; dn < 4; ++dn) {
      const char* vrow = vb + (16 * dn + r16) * 128;
      const int vsw = ((16 * dn + r16) & 7) << 4;
#pragma unroll
      for (int kn = 0; kn < 4; ++kn) {
        bf16x4 va = *(const bf16x4*)(vrow + ((32 * kn + 8 * g4) ^ vsw));
        O[dn] = mfma16x16x16(va, pb[kn], O[dn]);
      }
    }
    __syncthreads();
  }
#undef STAGE

  // epilogue: reduce lsum across the 4 lanes sharing q, normalize, write
  lsum += __shfl_xor(lsum, 16, 64);
  lsum += __shfl_xor(lsum, 32, 64);
  const float inv = 1.f / lsum;
  const int b = bh >> 4, h = bh & 15;
  const int t = q0 + 16 * w + r16;
#pragma unroll
  for (int n = 0; n < 4; ++n) {
    bf16x4 ov;
#pragma unroll
    for (int r = 0; r < 4; ++r) ov[r] = (bf16)(O[n][r] * inv);
    *(bf16x4*)(Og + ((size_t)(b * 2048 + t)) * 1024 + h * 64 + 16 * n + 4 * g4) = ov;
  }
}

// ---------------- launch ----------------

extern "C" void kernel_launch(void* const* d_in, const int* in_sizes, int n_in,
                              void* d_out, int out_size, void* d_ws, size_t ws_size,
                              hipStream_t stream) {
  const float* x     = (const float*)d_in[0];
  const float* w_qkv = (const float*)d_in[1];
  const float* b_qkv = (const float*)d_in[2];
  const float* w_out = (const float*)d_in[3];
  const float* b_out = (const float*)d_in[4];
  float* out = (float*)d_out;

  char* ws = (char*)d_ws;
  bf16* xb    = (bf16*)(ws);
  bf16* wqkvT = (bf16*)(ws + 8388608);
  bf16* woutT = (bf16*)(ws + 14680064);
  bf16* Qb    = (bf16*)(ws + 16777216);
  bf16* Kb    = (bf16*)(ws + 25165824);
  bf16* Vtb   = (bf16*)(ws + 33554432);
  bf16* attnb = (bf16*)(ws + 41943040);

  k_convert_x<<<4096 * 1024 / 4 / 256, 256, 0, stream>>>(x, xb, 4096 * 1024);
  k_transpose_bf16<<<dim3(3072 / 32, 1024 / 32), dim3(32, 8), 0, stream>>>(w_qkv, wqkvT, 1024, 3072);
  k_transpose_bf16<<<dim3(1024 / 32, 1024 / 32), dim3(32, 8), 0, stream>>>(w_out, woutT, 1024, 1024);
  k_gemm_qkv<<<32 * 24, 256, 0, stream>>>(xb, wqkvT, b_qkv, Qb, Kb, Vtb);
  k_attn<<<dim3(32, 32), 256, 0, stream>>>(Qb, Kb, Vtb, attnb);
  k_gemm_out<<<32 * 8, 256, 0, stream>>>(attnb, woutT, b_out, out, 4096, 1024, 1024);
}

// Round 8
// 153.399 us; speedup vs baseline: 1.4987x; 1.0459x over previous
//
#include <hip/hip_runtime.h>
#include <hip/hip_bf16.h>
#include <stdint.h>

// Problem: B=2, T=2048, D=1024, H=16, hd=64.  M = B*T = 4096.
// Pipeline: x->bf16 ; w^T->bf16 ; QKV gemm w/ fused bias+RoPE+head-split ; flash attn ; out gemm.
// Workspace layout (bytes), total 50,331,648 (48 MiB -- must stay < 64 MiB, see R2 post-mortem):
//   0        x_bf16   [4096][1024]
//   8388608  wqkvT    [3072][1024]
//   14680064 woutT    [1024][1024]
//   16777216 Q        [32][2048][64]   (pre-scaled by log2e/8, RoPE'd)
//   25165824 K        [32][2048][64]   (RoPE'd)
//   33554432 V^T      [32][64][2048]   (transposed; key dim INTERLEAVED per
//                                       64-block: pos(16a+4g+r)=16g+8(a>>1)+4(a&1)+r)
//   41943040 attn     [4096][1024]

typedef __bf16 bf16;
typedef __bf16 bf16x8 __attribute__((ext_vector_type(8)));
typedef __bf16 bf16x4 __attribute__((ext_vector_type(4)));
typedef short  s16x4  __attribute__((ext_vector_type(4)));
typedef float  f32x4  __attribute__((ext_vector_type(4)));

__device__ __forceinline__ void gload16(void* lds, const void* g) {
  // async global->LDS, 16B per lane, dest = wave-uniform base + lane*16
  __builtin_amdgcn_global_load_lds((__attribute__((address_space(1))) void*)(void*)g,
                                   (__attribute__((address_space(3))) void*)lds, 16, 0, 0);
}

__device__ __forceinline__ f32x4 mfma16x16x16(bf16x4 a, bf16x4 b, f32x4 c) {
  return __builtin_amdgcn_mfma_f32_16x16x16bf16_1k(
      __builtin_bit_cast(s16x4, a), __builtin_bit_cast(s16x4, b), c, 0, 0, 0);
}

// ---------------- conversion kernels ----------------

__global__ void k_convert_x(const float* __restrict__ x, bf16* __restrict__ xb, int n) {
  int i = (blockIdx.x * blockDim.x + threadIdx.x) * 4;
  if (i >= n) return;
  float4 v = *(const float4*)(x + i);
  bf16x4 o;
  o.x = (bf16)v.x; o.y = (bf16)v.y; o.z = (bf16)v.z; o.w = (bf16)v.w;
  *(bf16x4*)(xb + i) = o;
}

// in: fp32 [rows][cols]  ->  out: bf16 [cols][rows]
__global__ void k_transpose_bf16(const float* __restrict__ in, bf16* __restrict__ out,
                                 int rows, int cols) {
  __shared__ float t[32][33];
  int c0 = blockIdx.x * 32, r0 = blockIdx.y * 32;
  for (int i = threadIdx.y; i < 32; i += 8)
    t[i][threadIdx.x] = in[(size_t)(r0 + i) * cols + c0 + threadIdx.x];
  __syncthreads();
  for (int i = threadIdx.y; i < 32; i += 8)
    out[(size_t)(c0 + i) * rows + r0 + threadIdx.x] = (bf16)t[threadIdx.x][i];
}

// ---------------- QKV GEMM with fused bias + RoPE + head split ----------------

__global__ __launch_bounds__(256)
void k_gemm_qkv(const bf16* __restrict__ A, const bf16* __restrict__ Bt,
                const float* __restrict__ bias, bf16* __restrict__ Qd,
                bf16* __restrict__ Kd, bf16* __restrict__ Vtd) {
  alignas(16) __shared__ bf16 lds_a[128 * 32];
  alignas(16) __shared__ bf16 lds_b[128 * 32];
  const int tid = threadIdx.x;
  const int lane = tid & 63, w = tid >> 6;
  const int wr = w >> 1, wc = w & 1;
  // XCD-aware swizzle: 768 blocks = 8 XCDs x 96; contiguous br-chunks per XCD
  const int bid = blockIdx.x;
  const int swz = (bid & 7) * 96 + (bid >> 3);
  const int br = swz / 24, bc = swz % 24;
  const int r16 = lane & 15, g4 = lane >> 4;

  f32x4 acc[4][4] = {};
  const bf16* gA = A + (size_t)(br * 128 + (lane >> 2)) * 1024 + (lane & 3) * 8;
  const bf16* gB = Bt + (size_t)(bc * 128 + (lane >> 2)) * 1024 + (lane & 3) * 8;

  for (int kt = 0; kt < 32; ++kt) {
    const int ko = kt * 32;
#pragma unroll
    for (int it = 0; it < 2; ++it) {
      const int row0 = 16 * (4 * it + w);           // wave-uniform
      gload16(&lds_a[row0 * 32], gA + (size_t)row0 * 1024 + ko);
      gload16(&lds_b[row0 * 32], gB + (size_t)row0 * 1024 + ko);
    }
    __syncthreads();
    bf16x8 af[4], bfr[4];
#pragma unroll
    for (int m = 0; m < 4; ++m)
      af[m] = *(const bf16x8*)&lds_a[(wr * 64 + 16 * m + r16) * 32 + g4 * 8];
#pragma unroll
    for (int n = 0; n < 4; ++n)
      bfr[n] = *(const bf16x8*)&lds_b[(wc * 64 + 16 * n + r16) * 32 + g4 * 8];
#pragma unroll
    for (int m = 0; m < 4; ++m)
#pragma unroll
      for (int n = 0; n < 4; ++n)
        acc[m][n] = __builtin_amdgcn_mfma_f32_16x16x32_bf16(af[m], bfr[n], acc[m][n], 0, 0, 0);
    __syncthreads();
  }

  // ---- fused epilogue ----
  const int reg = bc >> 3;                       // 0=Q, 1=K, 2=V
  const int h = ((bc & 7) << 1) | wc;            // head 0..15
  const float bq = 0.125f * 1.4426950408889634f; // (1/sqrt(64)) * log2(e)
  const float Lc = 13.287712379549449f / 32.0f;  // log2(10000)/32
  const float if0 = exp2f(-(float)r16 * Lc);
  const float if1 = exp2f(-(float)(16 + r16) * Lc);
  float bv[4];
#pragma unroll
  for (int n = 0; n < 4; ++n) bv[n] = bias[bc * 128 + wc * 64 + 16 * n + r16];

  if (reg == 2) {
    // V: write V^T[b*16+h][d][t'] with interleaved key position within 64-block.
    // t = 64blk + 16a + 4g + r  ->  t' = 64blk + 16g + 8(a>>1) + 4(a&1) + r
    // bits of t: r=t&3, g=(t>>2)&3, a&1=(t>>4)&1, a>>1=(t>>5)&1.
#pragma unroll
    for (int m = 0; m < 4; ++m) {
      const int row0 = br * 128 + wr * 64 + 16 * m + 4 * g4;
      const int t0 = row0 & 2047, b = row0 >> 11;
      const int pos = (t0 & ~63) | (((t0 >> 2) & 3) << 4) | (((t0 >> 5) & 1) << 3) |
                      (((t0 >> 4) & 1) << 2);   // R7 bug: these two shifts were swapped
#pragma unroll
      for (int n = 0; n < 4; ++n) {
        bf16x4 pk;
#pragma unroll
        for (int r = 0; r < 4; ++r) pk[r] = (bf16)(acc[m][n][r] + bv[n]);
        *(bf16x4*)(Vtd + ((size_t)((b * 16 + h) * 64) + 16 * n + r16) * 2048 + pos) = pk;
      }
    }
  } else {
    bf16* dst = (reg == 0) ? Qd : Kd;
#pragma unroll
    for (int m = 0; m < 4; ++m) {
#pragma unroll
      for (int r = 0; r < 4; ++r) {
        const int row = br * 128 + wr * 64 + 16 * m + 4 * g4 + r;
        const int t = row & 2047, b = row >> 11;
        bf16* o = dst + ((size_t)(b * 16 + h) * 2048 + t) * 64;
        const float v0 = acc[m][0][r] + bv[0];
        const float v1 = acc[m][1][r] + bv[1];
        const float v2 = acc[m][2][r] + bv[2];
        const float v3 = acc[m][3][r] + bv[3];
        float s0, c0, s1, c1;
        const float tf = (float)t;
        sincosf(tf * if0, &s0, &c0);
        sincosf(tf * if1, &s1, &c1);
        float r0 = v0 * c0 - v2 * s0, r2 = v0 * s0 + v2 * c0;
        float r1 = v1 * c1 - v3 * s1, r3 = v1 * s1 + v3 * c1;
        if (reg == 0) { r0 *= bq; r1 *= bq; r2 *= bq; r3 *= bq; }
        o[r16]      = (bf16)r0;
        o[16 + r16] = (bf16)r1;
        o[32 + r16] = (bf16)r2;
        o[48 + r16] = (bf16)r3;
      }
    }
  }
}

// ---------------- out GEMM (m97-style 128x128, BK=32) ----------------

__global__ __launch_bounds__(256)
void k_gemm_out(const bf16* __restrict__ A, const bf16* __restrict__ Bt,
                const float* __restrict__ bias, float* __restrict__ Cp,
                int M, int N, int K) {
  alignas(16) __shared__ bf16 lds_a[128 * 32];
  alignas(16) __shared__ bf16 lds_b[128 * 32];
  const int tid = threadIdx.x;
  const int lane = tid & 63, w = tid >> 6;
  const int wr = w >> 1, wc = w & 1;
  const int nb = N >> 7;
  // XCD-aware swizzle (grid must be %8==0): contiguous chunks per XCD
  const int nwg = gridDim.x;
  const int bid = blockIdx.x;
  const int swz = (bid & 7) * (nwg >> 3) + (bid >> 3);
  const int br = swz / nb, bc = swz % nb;
  const int r16 = lane & 15, g4 = lane >> 4;

  f32x4 acc[4][4] = {};
  const int nk = K >> 5;
  const bf16* gA = A + (size_t)(br * 128 + (lane >> 2)) * K + (lane & 3) * 8;
  const bf16* gB = Bt + (size_t)(bc * 128 + (lane >> 2)) * K + (lane & 3) * 8;

  for (int kt = 0; kt < nk; ++kt) {
    const int ko = kt * 32;
#pragma unroll
    for (int it = 0; it < 2; ++it) {
      const int row0 = 16 * (4 * it + w);           // wave-uniform
      gload16(&lds_a[row0 * 32], gA + (size_t)row0 * K + ko);
      gload16(&lds_b[row0 * 32], gB + (size_t)row0 * K + ko);
    }
    __syncthreads();
    bf16x8 af[4], bfr[4];
#pragma unroll
    for (int m = 0; m < 4; ++m)
      af[m] = *(const bf16x8*)&lds_a[(wr * 64 + 16 * m + r16) * 32 + g4 * 8];
#pragma unroll
    for (int n = 0; n < 4; ++n)
      bfr[n] = *(const bf16x8*)&lds_b[(wc * 64 + 16 * n + r16) * 32 + g4 * 8];
#pragma unroll
    for (int m = 0; m < 4; ++m)
#pragma unroll
      for (int n = 0; n < 4; ++n)
        acc[m][n] = __builtin_amdgcn_mfma_f32_16x16x32_bf16(af[m], bfr[n], acc[m][n], 0, 0, 0);
    __syncthreads();
  }

#pragma unroll
  for (int m = 0; m < 4; ++m) {
    const int row = br * 128 + wr * 64 + 16 * m + 4 * g4;
#pragma unroll
    for (int n = 0; n < 4; ++n) {
      const int col = bc * 128 + wc * 64 + 16 * n + r16;
      const float bvv = bias[col];
#pragma unroll
      for (int r = 0; r < 4; ++r)
        Cp[(size_t)(row + r) * N + col] = acc[m][n][r] + bvv;
    }
  }
}

// ---------------- flash attention ----------------
// 1D grid 1024 (XCD-swizzled: 4 bh per XCD -> K/V L2-resident), 256 threads.
// Swapped QK^T (S^T = mfma(K,Q)); softmax in-lane; P^T register fragments feed
// PV (16x16x16) directly; V^T key-interleaved so PV A-frags are b128 reads
// with the conflict-free swizzle pattern; lsum computed BY the MFMA pipe via a
// virtual ones-row (d=64); defer-max (THR=8).

__global__ __launch_bounds__(256)
void k_attn(const bf16* __restrict__ Qg, const bf16* __restrict__ Kg,
            const bf16* __restrict__ Vtg, bf16* __restrict__ Og) {
  alignas(16) __shared__ bf16 kbuf[2][4096];   // [key 64][d 64] swizzled
  alignas(16) __shared__ bf16 vbuf[2][4096];   // [d 64][key 64 interleaved] swizzled
  const int tid = threadIdx.x, lane = tid & 63, w = tid >> 6;
  const int bid = blockIdx.x;
  const int swz = (bid & 7) * 128 + (bid >> 3);
  const int bh = swz >> 5, q0 = (swz & 31) * 64;
  const int r16 = lane & 15, g4 = lane >> 4;
  const char* Kb  = (const char*)(Kg  + (size_t)bh * 2048 * 64);
  const char* Vtb = (const char*)(Vtg + (size_t)bh * 64 * 2048);
  const bf16* Qb  = Qg + (size_t)bh * 2048 * 64;

  // staging geometry: per wave 2 chunks of 1KB each for K and V^T.
  const int rl = lane >> 3;
  const int colx = ((lane & 7) * 16) ^ (rl << 4);

  bf16x8 qf[2];
  {
    const int qrow = q0 + 16 * w + r16;
    qf[0] = *(const bf16x8*)(Qb + (size_t)qrow * 64 + g4 * 8);
    qf[1] = *(const bf16x8*)(Qb + (size_t)qrow * 64 + 32 + g4 * 8);
  }

  // O^T accumulator: O[dn] holds O[q=r16][d=16*dn+4*g4+r]; O4 = ones-row (lsum)
  f32x4 O[4] = {};
  f32x4 O4 = {};
  float m = -1e30f;
  bf16x4 ones = {};
  if (r16 == 0) { ones[0] = (bf16)1.f; ones[1] = (bf16)1.f; ones[2] = (bf16)1.f; ones[3] = (bf16)1.f; }

#define STAGE(bufi, t0)                                                          \
  {                                                                              \
    _Pragma("unroll")                                                            \
    for (int c = 0; c < 2; ++c) {                                                \
      const int row = 16 * w + 8 * c + rl;                                       \
      gload16(&kbuf[bufi][(2 * w + c) * 512],                                    \
              Kb + (size_t)((t0) + row) * 128 + colx);                           \
      gload16(&vbuf[bufi][(2 * w + c) * 512],                                    \
              Vtb + (size_t)row * 4096 + (size_t)(t0) * 2 + colx);               \
    }                                                                            \
  }

  STAGE(0, 0);
  __syncthreads();

  const int rsw = (r16 & 7) << 4;           // read-side swizzle for r16-based rows

#pragma unroll 1
  for (int it = 0; it < 32; ++it) {
    const int bsel = it & 1;
    if (it + 1 < 32) STAGE(bsel ^ 1, (it + 1) * 64);
    const char* kb = (const char*)kbuf[bsel] + r16 * 128;
    const char* vb = (const char*)vbuf[bsel] + r16 * 128;

    // S^T = K Q^T : lane holds S^T[key=16n+4g4+r][q=r16]
    f32x4 S[4];
#pragma unroll
    for (int n = 0; n < 4; ++n) {
      bf16x8 kb0 = *(const bf16x8*)(kb + n * 2048 + ((g4 * 16) ^ rsw));
      bf16x8 kb1 = *(const bf16x8*)(kb + n * 2048 + ((64 + g4 * 16) ^ rsw));
      f32x4 s = {};
      s = __builtin_amdgcn_mfma_f32_16x16x32_bf16(kb0, qf[0], s, 0, 0, 0);
      s = __builtin_amdgcn_mfma_f32_16x16x32_bf16(kb1, qf[1], s, 0, 0, 0);
      S[n] = s;
    }

    // in-lane max over this lane's 16 scores (max3-friendly triples)
    float pmax = fmaxf(
        fmaxf(fmaxf(fmaxf(S[0][0], S[0][1]), S[0][2]),
              fmaxf(fmaxf(S[0][3], S[1][0]), S[1][1])),
        fmaxf(fmaxf(fmaxf(S[1][2], S[1][3]), S[2][0]),
              fmaxf(fmaxf(S[2][1], S[2][2]), S[2][3])));
    pmax = fmaxf(pmax, fmaxf(fmaxf(S[3][0], S[3][1]), fmaxf(S[3][2], S[3][3])));

    // defer-max: rescale only when max grew beyond THR=8 (exp2 domain)
    if (!__all(pmax - m <= 8.0f)) {
      float gmax = pmax;
      gmax = fmaxf(gmax, __shfl_xor(gmax, 16, 64));
      gmax = fmaxf(gmax, __shfl_xor(gmax, 32, 64));
      const float mn = fmaxf(m, gmax);
      const float alpha = exp2f(m - mn);
      m = mn;
#pragma unroll
      for (int n = 0; n < 4; ++n)
#pragma unroll
        for (int r = 0; r < 4; ++r) O[n][r] *= alpha;
      O4[0] *= alpha;
    }

    // P = exp2(S - m); P^T frags feed PV directly (no LDS, no row-sum VALU)
    bf16x4 pb[4];
#pragma unroll
    for (int n = 0; n < 4; ++n)
#pragma unroll
      for (int r = 0; r < 4; ++r) pb[n][r] = (bf16)exp2f(S[n][r] - m);

    // O^T += V^T P^T : d-subtile dn; key-interleaved V -> 2 b128 reads cover
    // all 4 kn A-frags.  Plus ones-row mfma accumulates lsum into O4[0].
#pragma unroll
    for (int dn = 0; dn < 4; ++dn) {
      bf16x8 v0 = *(const bf16x8*)(vb + dn * 2048 + ((32 * g4) ^ rsw));
      bf16x8 v1 = *(const bf16x8*)(vb + dn * 2048 + ((32 * g4 + 16) ^ rsw));
      O[dn] = mfma16x16x16(__builtin_shufflevector(v0, v0, 0, 1, 2, 3), pb[0], O[dn]);
      O[dn] = mfma16x16x16(__builtin_shufflevector(v0, v0, 4, 5, 6, 7), pb[1], O[dn]);
      O[dn] = mfma16x16x16(__builtin_shufflevector(v1, v1, 0, 1, 2, 3), pb[2], O[dn]);
      O[dn] = mfma16x16x16(__builtin_shufflevector(v1, v1, 4, 5, 6, 7), pb[3], O[dn]);
    }
#pragma unroll
    for (int kn = 0; kn < 4; ++kn) O4 = mfma16x16x16(ones, pb[kn], O4);
    __syncthreads();
  }
#undef STAGE

  // epilogue: lsum for q lives in lane (q, g4=0)'s O4[0]; broadcast, normalize
  const float ls = __shfl(O4[0], r16, 64);
  const float inv = 1.f / ls;
  const int b = bh >> 4, h = bh & 15;
  const int t = q0 + 16 * w + r16;
#pragma unroll
  for (int n = 0; n < 4; ++n) {
    bf16x4 ov;
#pragma unroll
    for (int r = 0; r < 4; ++r) ov[r] = (bf16)(O[n][r] * inv);
    *(bf16x4*)(Og + ((size_t)(b * 2048 + t)) * 1024 + h * 64 + 16 * n + 4 * g4) = ov;
  }
}

// ---------------- launch ----------------

extern "C" void kernel_launch(void* const* d_in, const int* in_sizes, int n_in,
                              void* d_out, int out_size, void* d_ws, size_t ws_size,
                              hipStream_t stream) {
  const float* x     = (const float*)d_in[0];
  const float* w_qkv = (const float*)d_in[1];
  const float* b_qkv = (const float*)d_in[2];
  const float* w_out = (const float*)d_in[3];
  const float* b_out = (const float*)d_in[4];
  float* out = (float*)d_out;

  char* ws = (char*)d_ws;
  bf16* xb    = (bf16*)(ws);
  bf16* wqkvT = (bf16*)(ws + 8388608);
  bf16* woutT = (bf16*)(ws + 14680064);
  bf16* Qb    = (bf16*)(ws + 16777216);
  bf16* Kb    = (bf16*)(ws + 25165824);
  bf16* Vtb   = (bf16*)(ws + 33554432);
  bf16* attnb = (bf16*)(ws + 41943040);

  k_convert_x<<<4096 * 1024 / 4 / 256, 256, 0, stream>>>(x, xb, 4096 * 1024);
  k_transpose_bf16<<<dim3(3072 / 32, 1024 / 32), dim3(32, 8), 0, stream>>>(w_qkv, wqkvT, 1024, 3072);
  k_transpose_bf16<<<dim3(1024 / 32, 1024 / 32), dim3(32, 8), 0, stream>>>(w_out, woutT, 1024, 1024);
  k_gemm_qkv<<<32 * 24, 256, 0, stream>>>(xb, wqkvT, b_qkv, Qb, Kb, Vtb);
  k_attn<<<1024, 256, 0, stream>>>(Qb, Kb, Vtb, attnb);
  k_gemm_out<<<32 * 8, 256, 0, stream>>>(attnb, woutT, b_out, out, 4096, 1024, 1024);
}

// Round 9
// 146.917 us; speedup vs baseline: 1.5648x; 1.0441x over previous
//
#include <hip/hip_runtime.h>
#include <hip/hip_bf16.h>
#include <stdint.h>

// Problem: B=2, T=2048, D=1024, H=16, hd=64.  M = B*T = 4096.
// Pipeline: x->bf16 ; w^T->bf16 ; QKV gemm w/ fused bias+RoPE+head-split ; flash attn ; out gemm.
// Workspace layout (bytes), total 50,331,648 (48 MiB -- must stay < 64 MiB, see R2 post-mortem):
//   0        x_bf16   [4096][1024]
//   8388608  wqkvT    [3072][1024]
//   14680064 woutT    [1024][1024]
//   16777216 Q        [32][2048][64]   (pre-scaled by log2e/8, RoPE'd)
//   25165824 K        [32][2048][64]   (RoPE'd)
//   33554432 V^T      [32][64][2048]   (transposed; key dim INTERLEAVED per
//                                       64-block: pos(16a+4g+r)=16g+8(a>>1)+4(a&1)+r)
//   41943040 attn     [4096][1024]

typedef __bf16 bf16;
typedef __bf16 bf16x8 __attribute__((ext_vector_type(8)));
typedef __bf16 bf16x4 __attribute__((ext_vector_type(4)));
typedef short  s16x4  __attribute__((ext_vector_type(4)));
typedef float  f32x4  __attribute__((ext_vector_type(4)));

__device__ __forceinline__ void gload16(void* lds, const void* g) {
  // async global->LDS, 16B per lane, dest = wave-uniform base + lane*16
  __builtin_amdgcn_global_load_lds((__attribute__((address_space(1))) void*)(void*)g,
                                   (__attribute__((address_space(3))) void*)lds, 16, 0, 0);
}

// ---------------- conversion kernels ----------------

__global__ void k_convert_x(const float* __restrict__ x, bf16* __restrict__ xb, int n) {
  int i = (blockIdx.x * blockDim.x + threadIdx.x) * 4;
  if (i >= n) return;
  float4 v = *(const float4*)(x + i);
  bf16x4 o;
  o.x = (bf16)v.x; o.y = (bf16)v.y; o.z = (bf16)v.z; o.w = (bf16)v.w;
  *(bf16x4*)(xb + i) = o;
}

// in: fp32 [rows][cols]  ->  out: bf16 [cols][rows]
__global__ void k_transpose_bf16(const float* __restrict__ in, bf16* __restrict__ out,
                                 int rows, int cols) {
  __shared__ float t[32][33];
  int c0 = blockIdx.x * 32, r0 = blockIdx.y * 32;
  for (int i = threadIdx.y; i < 32; i += 8)
    t[i][threadIdx.x] = in[(size_t)(r0 + i) * cols + c0 + threadIdx.x];
  __syncthreads();
  for (int i = threadIdx.y; i < 32; i += 8)
    out[(size_t)(c0 + i) * rows + r0 + threadIdx.x] = (bf16)t[threadIdx.x][i];
}

// ---------------- QKV GEMM with fused bias + RoPE + head split ----------------

__global__ __launch_bounds__(256)
void k_gemm_qkv(const bf16* __restrict__ A, const bf16* __restrict__ Bt,
                const float* __restrict__ bias, bf16* __restrict__ Qd,
                bf16* __restrict__ Kd, bf16* __restrict__ Vtd) {
  alignas(16) __shared__ bf16 lds_a[128 * 32];
  alignas(16) __shared__ bf16 lds_b[128 * 32];
  const int tid = threadIdx.x;
  const int lane = tid & 63, w = tid >> 6;
  const int wr = w >> 1, wc = w & 1;
  // XCD-aware swizzle: 768 blocks = 8 XCDs x 96; contiguous br-chunks per XCD
  const int bid = blockIdx.x;
  const int swz = (bid & 7) * 96 + (bid >> 3);
  const int br = swz / 24, bc = swz % 24;
  const int r16 = lane & 15, g4 = lane >> 4;

  f32x4 acc[4][4] = {};
  const bf16* gA = A + (size_t)(br * 128 + (lane >> 2)) * 1024 + (lane & 3) * 8;
  const bf16* gB = Bt + (size_t)(bc * 128 + (lane >> 2)) * 1024 + (lane & 3) * 8;

  for (int kt = 0; kt < 32; ++kt) {
    const int ko = kt * 32;
#pragma unroll
    for (int it = 0; it < 2; ++it) {
      const int row0 = 16 * (4 * it + w);           // wave-uniform
      gload16(&lds_a[row0 * 32], gA + (size_t)row0 * 1024 + ko);
      gload16(&lds_b[row0 * 32], gB + (size_t)row0 * 1024 + ko);
    }
    __syncthreads();
    bf16x8 af[4], bfr[4];
#pragma unroll
    for (int m = 0; m < 4; ++m)
      af[m] = *(const bf16x8*)&lds_a[(wr * 64 + 16 * m + r16) * 32 + g4 * 8];
#pragma unroll
    for (int n = 0; n < 4; ++n)
      bfr[n] = *(const bf16x8*)&lds_b[(wc * 64 + 16 * n + r16) * 32 + g4 * 8];
#pragma unroll
    for (int m = 0; m < 4; ++m)
#pragma unroll
      for (int n = 0; n < 4; ++n)
        acc[m][n] = __builtin_amdgcn_mfma_f32_16x16x32_bf16(af[m], bfr[n], acc[m][n], 0, 0, 0);
    __syncthreads();
  }

  // ---- fused epilogue ----
  const int reg = bc >> 3;                       // 0=Q, 1=K, 2=V
  const int h = ((bc & 7) << 1) | wc;            // head 0..15
  const float bq = 0.125f * 1.4426950408889634f; // (1/sqrt(64)) * log2(e)
  const float Lc = 13.287712379549449f / 32.0f;  // log2(10000)/32
  const float if0 = exp2f(-(float)r16 * Lc);
  const float if1 = exp2f(-(float)(16 + r16) * Lc);
  float bv[4];
#pragma unroll
  for (int n = 0; n < 4; ++n) bv[n] = bias[bc * 128 + wc * 64 + 16 * n + r16];

  if (reg == 2) {
    // V: write V^T[b*16+h][d][t'] with interleaved key position within 64-block.
    // t = 64blk + 16a + 4g + r  ->  t' = 64blk + 16g + 8(a>>1) + 4(a&1) + r
#pragma unroll
    for (int m = 0; m < 4; ++m) {
      const int row0 = br * 128 + wr * 64 + 16 * m + 4 * g4;
      const int t0 = row0 & 2047, b = row0 >> 11;
      const int pos = (t0 & ~63) | (((t0 >> 2) & 3) << 4) | (((t0 >> 5) & 1) << 3) |
                      (((t0 >> 4) & 1) << 2);
#pragma unroll
      for (int n = 0; n < 4; ++n) {
        bf16x4 pk;
#pragma unroll
        for (int r = 0; r < 4; ++r) pk[r] = (bf16)(acc[m][n][r] + bv[n]);
        *(bf16x4*)(Vtd + ((size_t)((b * 16 + h) * 64) + 16 * n + r16) * 2048 + pos) = pk;
      }
    }
  } else {
    bf16* dst = (reg == 0) ? Qd : Kd;
#pragma unroll
    for (int m = 0; m < 4; ++m) {
#pragma unroll
      for (int r = 0; r < 4; ++r) {
        const int row = br * 128 + wr * 64 + 16 * m + 4 * g4 + r;
        const int t = row & 2047, b = row >> 11;
        bf16* o = dst + ((size_t)(b * 16 + h) * 2048 + t) * 64;
        const float v0 = acc[m][0][r] + bv[0];
        const float v1 = acc[m][1][r] + bv[1];
        const float v2 = acc[m][2][r] + bv[2];
        const float v3 = acc[m][3][r] + bv[3];
        float s0, c0, s1, c1;
        const float tf = (float)t;
        sincosf(tf * if0, &s0, &c0);
        sincosf(tf * if1, &s1, &c1);
        float r0 = v0 * c0 - v2 * s0, r2 = v0 * s0 + v2 * c0;
        float r1 = v1 * c1 - v3 * s1, r3 = v1 * s1 + v3 * c1;
        if (reg == 0) { r0 *= bq; r1 *= bq; r2 *= bq; r3 *= bq; }
        o[r16]      = (bf16)r0;
        o[16 + r16] = (bf16)r1;
        o[32 + r16] = (bf16)r2;
        o[48 + r16] = (bf16)r3;
      }
    }
  }
}

// ---------------- out GEMM (m97-style 128x128, BK=32) ----------------

__global__ __launch_bounds__(256)
void k_gemm_out(const bf16* __restrict__ A, const bf16* __restrict__ Bt,
                const float* __restrict__ bias, float* __restrict__ Cp,
                int M, int N, int K) {
  alignas(16) __shared__ bf16 lds_a[128 * 32];
  alignas(16) __shared__ bf16 lds_b[128 * 32];
  const int tid = threadIdx.x;
  const int lane = tid & 63, w = tid >> 6;
  const int wr = w >> 1, wc = w & 1;
  const int nb = N >> 7;
  // XCD-aware swizzle (grid must be %8==0): contiguous chunks per XCD
  const int nwg = gridDim.x;
  const int bid = blockIdx.x;
  const int swz = (bid & 7) * (nwg >> 3) + (bid >> 3);
  const int br = swz / nb, bc = swz % nb;
  const int r16 = lane & 15, g4 = lane >> 4;

  f32x4 acc[4][4] = {};
  const int nk = K >> 5;
  const bf16* gA = A + (size_t)(br * 128 + (lane >> 2)) * K + (lane & 3) * 8;
  const bf16* gB = Bt + (size_t)(bc * 128 + (lane >> 2)) * K + (lane & 3) * 8;

  for (int kt = 0; kt < nk; ++kt) {
    const int ko = kt * 32;
#pragma unroll
    for (int it = 0; it < 2; ++it) {
      const int row0 = 16 * (4 * it + w);           // wave-uniform
      gload16(&lds_a[row0 * 32], gA + (size_t)row0 * K + ko);
      gload16(&lds_b[row0 * 32], gB + (size_t)row0 * K + ko);
    }
    __syncthreads();
    bf16x8 af[4], bfr[4];
#pragma unroll
    for (int m = 0; m < 4; ++m)
      af[m] = *(const bf16x8*)&lds_a[(wr * 64 + 16 * m + r16) * 32 + g4 * 8];
#pragma unroll
    for (int n = 0; n < 4; ++n)
      bfr[n] = *(const bf16x8*)&lds_b[(wc * 64 + 16 * n + r16) * 32 + g4 * 8];
#pragma unroll
    for (int m = 0; m < 4; ++m)
#pragma unroll
      for (int n = 0; n < 4; ++n)
        acc[m][n] = __builtin_amdgcn_mfma_f32_16x16x32_bf16(af[m], bfr[n], acc[m][n], 0, 0, 0);
    __syncthreads();
  }

#pragma unroll
  for (int m = 0; m < 4; ++m) {
    const int row = br * 128 + wr * 64 + 16 * m + 4 * g4;
#pragma unroll
    for (int n = 0; n < 4; ++n) {
      const int col = bc * 128 + wc * 64 + 16 * n + r16;
      const float bvv = bias[col];
#pragma unroll
      for (int r = 0; r < 4; ++r)
        Cp[(size_t)(row + r) * N + col] = acc[m][n][r] + bvv;
    }
  }
}

// ---------------- flash attention ----------------
// 1D grid 512 (XCD-swizzled), 256 threads (4 waves).  Each wave owns 32 q-rows
// (2 groups of 16) -> K/V LDS reads amortized 2x, PV via full-K 16x16x32 mfma
// (interleaved V layout makes the b128 read a valid K=32 A-fragment, key-map
// 16(j>>2)+4g4+(j&3) == concat(pb[2i],pb[2i+1])).  lsum via ones-row mfma.
// Swapped QK^T; in-lane softmax; defer-max (THR=8).

__global__ __launch_bounds__(256)
void k_attn(const bf16* __restrict__ Qg, const bf16* __restrict__ Kg,
            const bf16* __restrict__ Vtg, bf16* __restrict__ Og) {
  alignas(16) __shared__ bf16 kbuf[2][4096];   // [key 64][d 64] swizzled
  alignas(16) __shared__ bf16 vbuf[2][4096];   // [d 64][key 64 interleaved] swizzled
  const int tid = threadIdx.x, lane = tid & 63, w = tid >> 6;
  const int bid = blockIdx.x;
  const int swz = (bid & 7) * 64 + (bid >> 3);
  const int bh = swz >> 4, q0 = (swz & 15) * 128;
  const int r16 = lane & 15, g4 = lane >> 4;
  const char* Kb  = (const char*)(Kg  + (size_t)bh * 2048 * 64);
  const char* Vtb = (const char*)(Vtg + (size_t)bh * 64 * 2048);
  const bf16* Qb  = Qg + (size_t)bh * 2048 * 64;

  // staging geometry: per wave 2 chunks of 1KB each for K and V^T.
  const int rl = lane >> 3;
  const int colx = ((lane & 7) * 16) ^ (rl << 4);

  bf16x8 qf[2][2];
#pragma unroll
  for (int g = 0; g < 2; ++g) {
    const int qrow = q0 + 64 * g + 16 * w + r16;
    qf[g][0] = *(const bf16x8*)(Qb + (size_t)qrow * 64 + g4 * 8);
    qf[g][1] = *(const bf16x8*)(Qb + (size_t)qrow * 64 + 32 + g4 * 8);
  }

  // O^T accumulators per group: O[g][dn] holds O[q=r16][d=16*dn+4*g4+r]
  f32x4 O[2][4] = {};
  f32x4 O4[2] = {};                     // ones-row lsum accumulators
  float m0 = -1e30f, m1 = -1e30f;
  bf16x8 ones8 = {};
  if (r16 == 0)
#pragma unroll
    for (int j = 0; j < 8; ++j) ones8[j] = (bf16)1.f;

#define STAGE(bufi, t0)                                                          \
  {                                                                              \
    _Pragma("unroll")                                                            \
    for (int c = 0; c < 2; ++c) {                                                \
      const int row = 16 * w + 8 * c + rl;                                       \
      gload16(&kbuf[bufi][(2 * w + c) * 512],                                    \
              Kb + (size_t)((t0) + row) * 128 + colx);                           \
      gload16(&vbuf[bufi][(2 * w + c) * 512],                                    \
              Vtb + (size_t)row * 4096 + (size_t)(t0) * 2 + colx);               \
    }                                                                            \
  }

  STAGE(0, 0);
  __syncthreads();

  const int rsw = (r16 & 7) << 4;           // read-side swizzle for r16-based rows

#pragma unroll 1
  for (int it = 0; it < 32; ++it) {
    const int bsel = it & 1;
    if (it + 1 < 32) STAGE(bsel ^ 1, (it + 1) * 64);
    const char* kb = (const char*)kbuf[bsel] + r16 * 128;
    const char* vb = (const char*)vbuf[bsel] + r16 * 128;

    // S^T = K Q^T : lane holds S^T[key=16n+4g4+r][q=r16]; kb frags shared by groups
    f32x4 S0[4], S1[4];
#pragma unroll
    for (int n = 0; n < 4; ++n) {
      bf16x8 kb0 = *(const bf16x8*)(kb + n * 2048 + ((g4 * 16) ^ rsw));
      bf16x8 kb1 = *(const bf16x8*)(kb + n * 2048 + ((64 + g4 * 16) ^ rsw));
      f32x4 s = {};
      s = __builtin_amdgcn_mfma_f32_16x16x32_bf16(kb0, qf[0][0], s, 0, 0, 0);
      s = __builtin_amdgcn_mfma_f32_16x16x32_bf16(kb1, qf[0][1], s, 0, 0, 0);
      S0[n] = s;
      f32x4 t = {};
      t = __builtin_amdgcn_mfma_f32_16x16x32_bf16(kb0, qf[1][0], t, 0, 0, 0);
      t = __builtin_amdgcn_mfma_f32_16x16x32_bf16(kb1, qf[1][1], t, 0, 0, 0);
      S1[n] = t;
    }

    // in-lane max per group
    float pmax0 = fmaxf(
        fmaxf(fmaxf(fmaxf(S0[0][0], S0[0][1]), S0[0][2]),
              fmaxf(fmaxf(S0[0][3], S0[1][0]), S0[1][1])),
        fmaxf(fmaxf(fmaxf(S0[1][2], S0[1][3]), S0[2][0]),
              fmaxf(fmaxf(S0[2][1], S0[2][2]), S0[2][3])));
    pmax0 = fmaxf(pmax0, fmaxf(fmaxf(S0[3][0], S0[3][1]), fmaxf(S0[3][2], S0[3][3])));
    float pmax1 = fmaxf(
        fmaxf(fmaxf(fmaxf(S1[0][0], S1[0][1]), S1[0][2]),
              fmaxf(fmaxf(S1[0][3], S1[1][0]), S1[1][1])),
        fmaxf(fmaxf(fmaxf(S1[1][2], S1[1][3]), S1[2][0]),
              fmaxf(fmaxf(S1[2][1], S1[2][2]), S1[2][3])));
    pmax1 = fmaxf(pmax1, fmaxf(fmaxf(S1[3][0], S1[3][1]), fmaxf(S1[3][2], S1[3][3])));

    // defer-max: rescale only when either group's max grew beyond THR=8
    if (!__all(fmaxf(pmax0 - m0, pmax1 - m1) <= 8.0f)) {
      float gm0 = pmax0, gm1 = pmax1;
      gm0 = fmaxf(gm0, __shfl_xor(gm0, 16, 64));
      gm0 = fmaxf(gm0, __shfl_xor(gm0, 32, 64));
      gm1 = fmaxf(gm1, __shfl_xor(gm1, 16, 64));
      gm1 = fmaxf(gm1, __shfl_xor(gm1, 32, 64));
      const float mn0 = fmaxf(m0, gm0), mn1 = fmaxf(m1, gm1);
      const float a0 = exp2f(m0 - mn0), a1 = exp2f(m1 - mn1);
      m0 = mn0; m1 = mn1;
#pragma unroll
      for (int n = 0; n < 4; ++n)
#pragma unroll
        for (int r = 0; r < 4; ++r) { O[0][n][r] *= a0; O[1][n][r] *= a1; }
      O4[0][0] *= a0; O4[1][0] *= a1;
    }

    // P = exp2(S - m), packed as K=32 B-fragments: pbX[i] = (pb[2i] | pb[2i+1])
    bf16x8 pb0[2], pb1[2];
#pragma unroll
    for (int n = 0; n < 4; ++n)
#pragma unroll
      for (int r = 0; r < 4; ++r) {
        pb0[n >> 1][(n & 1) * 4 + r] = (bf16)exp2f(S0[n][r] - m0);
        pb1[n >> 1][(n & 1) * 4 + r] = (bf16)exp2f(S1[n][r] - m1);
      }

    // O^T += V^T P^T : v0/v1 b128 reads ARE K=32 A-fragments (interleaved V);
    // shared across both q-groups.
#pragma unroll
    for (int dn = 0; dn < 4; ++dn) {
      bf16x8 v0 = *(const bf16x8*)(vb + dn * 2048 + ((32 * g4) ^ rsw));
      bf16x8 v1 = *(const bf16x8*)(vb + dn * 2048 + ((32 * g4 + 16) ^ rsw));
      O[0][dn] = __builtin_amdgcn_mfma_f32_16x16x32_bf16(v0, pb0[0], O[0][dn], 0, 0, 0);
      O[0][dn] = __builtin_amdgcn_mfma_f32_16x16x32_bf16(v1, pb0[1], O[0][dn], 0, 0, 0);
      O[1][dn] = __builtin_amdgcn_mfma_f32_16x16x32_bf16(v0, pb1[0], O[1][dn], 0, 0, 0);
      O[1][dn] = __builtin_amdgcn_mfma_f32_16x16x32_bf16(v1, pb1[1], O[1][dn], 0, 0, 0);
    }
    O4[0] = __builtin_amdgcn_mfma_f32_16x16x32_bf16(ones8, pb0[0], O4[0], 0, 0, 0);
    O4[0] = __builtin_amdgcn_mfma_f32_16x16x32_bf16(ones8, pb0[1], O4[0], 0, 0, 0);
    O4[1] = __builtin_amdgcn_mfma_f32_16x16x32_bf16(ones8, pb1[0], O4[1], 0, 0, 0);
    O4[1] = __builtin_amdgcn_mfma_f32_16x16x32_bf16(ones8, pb1[1], O4[1], 0, 0, 0);
    __syncthreads();
  }
#undef STAGE

  // epilogue: lsum for q lives in lane (q, g4=0)'s O4[g][0]; broadcast, normalize
  const int b = bh >> 4, h = bh & 15;
#pragma unroll
  for (int g = 0; g < 2; ++g) {
    const float ls = __shfl(O4[g][0], r16, 64);
    const float inv = 1.f / ls;
    const int t = q0 + 64 * g + 16 * w + r16;
#pragma unroll
    for (int n = 0; n < 4; ++n) {
      bf16x4 ov;
#pragma unroll
      for (int r = 0; r < 4; ++r) ov[r] = (bf16)(O[g][n][r] * inv);
      *(bf16x4*)(Og + ((size_t)(b * 2048 + t)) * 1024 + h * 64 + 16 * n + 4 * g4) = ov;
    }
  }
}

// ---------------- launch ----------------

extern "C" void kernel_launch(void* const* d_in, const int* in_sizes, int n_in,
                              void* d_out, int out_size, void* d_ws, size_t ws_size,
                              hipStream_t stream) {
  const float* x     = (const float*)d_in[0];
  const float* w_qkv = (const float*)d_in[1];
  const float* b_qkv = (const float*)d_in[2];
  const float* w_out = (const float*)d_in[3];
  const float* b_out = (const float*)d_in[4];
  float* out = (float*)d_out;

  char* ws = (char*)d_ws;
  bf16* xb    = (bf16*)(ws);
  bf16* wqkvT = (bf16*)(ws + 8388608);
  bf16* woutT = (bf16*)(ws + 14680064);
  bf16* Qb    = (bf16*)(ws + 16777216);
  bf16* Kb    = (bf16*)(ws + 25165824);
  bf16* Vtb   = (bf16*)(ws + 33554432);
  bf16* attnb = (bf16*)(ws + 41943040);

  k_convert_x<<<4096 * 1024 / 4 / 256, 256, 0, stream>>>(x, xb, 4096 * 1024);
  k_transpose_bf16<<<dim3(3072 / 32, 1024 / 32), dim3(32, 8), 0, stream>>>(w_qkv, wqkvT, 1024, 3072);
  k_transpose_bf16<<<dim3(1024 / 32, 1024 / 32), dim3(32, 8), 0, stream>>>(w_out, woutT, 1024, 1024);
  k_gemm_qkv<<<32 * 24, 256, 0, stream>>>(xb, wqkvT, b_qkv, Qb, Kb, Vtb);
  k_attn<<<512, 256, 0, stream>>>(Qb, Kb, Vtb, attnb);
  k_gemm_out<<<32 * 8, 256, 0, stream>>>(attnb, woutT, b_out, out, 4096, 1024, 1024);
}